// Round 4
// baseline (788.333 us; speedup 1.0000x reference)
//
#include <hip/hip_runtime.h>
#include <math.h>

#define NN 50000
#define NE 800000
#define DIM 128
#define NH 8
#define HD 16

// ---- K1: QKV projection. lane = output column (coalesced stores).
// x rows read via wave-uniform address -> scalar loads; W per-lane in VGPRs.
// Each wave: 32 rows x 64 cols x 3 mats. Block: 64 rows (2 row-waves x 2 col-waves).
__global__ __launch_bounds__(256) void qkv_kernel(
    const float* __restrict__ x,
    const float* __restrict__ Wq, const float* __restrict__ bq,
    const float* __restrict__ Wk, const float* __restrict__ bk,
    const float* __restrict__ Wv, const float* __restrict__ bv,
    float* __restrict__ q, float* __restrict__ k, float* __restrict__ v)
{
    const int tid  = threadIdx.x;
    const int lane = tid & 63;
    const int colw = __builtin_amdgcn_readfirstlane((tid >> 6) & 1);
    const int roww = __builtin_amdgcn_readfirstlane(tid >> 7);
    const int j = colw * 64 + lane;                 // output column 0..127
    const int rbase = blockIdx.x * 64 + roww * 32;  // 32 rows per wave

    float acc0[32], acc1[32], acc2[32];
#pragma unroll
    for (int r = 0; r < 32; ++r) { acc0[r] = 0.f; acc1[r] = 0.f; acc2[r] = 0.f; }

    const float* wqp = Wq + (size_t)j * DIM;
    const float* wkp = Wk + (size_t)j * DIM;
    const float* wvp = Wv + (size_t)j * DIM;

    for (int k0 = 0; k0 < DIM; k0 += 16) {
        float4 wq4[4], wk4[4], wv4[4];
#pragma unroll
        for (int u = 0; u < 4; ++u) {
            wq4[u] = ((const float4*)(wqp + k0))[u];
            wk4[u] = ((const float4*)(wkp + k0))[u];
            wv4[u] = ((const float4*)(wvp + k0))[u];
        }
#pragma unroll
        for (int r = 0; r < 32; ++r) {
            int row = rbase + r; if (row >= NN) row = NN - 1;   // uniform clamp
            const float4* xr = (const float4*)(x + (size_t)row * DIM + k0);
            float4 xv[4];
#pragma unroll
            for (int u = 0; u < 4; ++u) xv[u] = xr[u];
            float a0 = acc0[r], a1 = acc1[r], a2 = acc2[r];
#pragma unroll
            for (int u = 0; u < 4; ++u) {
                a0 += xv[u].x * wq4[u].x; a1 += xv[u].x * wk4[u].x; a2 += xv[u].x * wv4[u].x;
                a0 += xv[u].y * wq4[u].y; a1 += xv[u].y * wk4[u].y; a2 += xv[u].y * wv4[u].y;
                a0 += xv[u].z * wq4[u].z; a1 += xv[u].z * wk4[u].z; a2 += xv[u].z * wv4[u].z;
                a0 += xv[u].w * wq4[u].w; a1 += xv[u].w * wk4[u].w; a2 += xv[u].w * wv4[u].w;
            }
            acc0[r] = a0; acc1[r] = a1; acc2[r] = a2;
        }
    }

    const float biasq = bq[j], biask = bk[j], biasv = bv[j];
#pragma unroll
    for (int r = 0; r < 32; ++r) {
        int row = rbase + r;
        if (row < NN) {
            q[(size_t)row * DIM + j] = acc0[r] + biasq;
            k[(size_t)row * DIM + j] = acc1[r] + biask;
            v[(size_t)row * DIM + j] = acc2[r] + biasv;
        }
    }
}

// ---- K2: histogram of edges per target node ----
__global__ __launch_bounds__(256) void hist_kernel(
    const int* __restrict__ tgt, int* __restrict__ cnt)
{
    int e = blockIdx.x * 256 + threadIdx.x;
    if (e < NE) atomicAdd(cnt + tgt[e], 1);
}

// ---- K3: single-block exclusive scan -> off, cursor ----
__global__ __launch_bounds__(1024) void scan_kernel(
    const int* __restrict__ cnt, int* __restrict__ off, int* __restrict__ cursor)
{
    __shared__ int wsum[16];
    __shared__ int carry_s;
    const int tid = threadIdx.x;
    const int lane = tid & 63;
    const int wid = tid >> 6;
    if (tid == 0) carry_s = 0;
    __syncthreads();
    for (int base = 0; base < NN; base += 1024) {
        int i = base + tid;
        int orig = (i < NN) ? cnt[i] : 0;
        int vv = orig;
#pragma unroll
        for (int d = 1; d < 64; d <<= 1) {
            int t = __shfl_up(vv, d);
            if (lane >= d) vv += t;
        }
        if (lane == 63) wsum[wid] = vv;
        __syncthreads();
        if (wid == 0) {
            int wv = (lane < 16) ? wsum[lane] : 0;
#pragma unroll
            for (int d = 1; d < 16; d <<= 1) {
                int t = __shfl_up(wv, d);
                if (lane >= d) wv += t;
            }
            if (lane < 16) wsum[lane] = wv;
        }
        __syncthreads();
        int wave_excl = (wid == 0) ? 0 : wsum[wid - 1];
        int carry = carry_s;
        int excl = carry + wave_excl + (vv - orig);
        if (i < NN) { off[i] = excl; cursor[i] = excl; }
        __syncthreads();
        if (tid == 1023) carry_s = carry + wsum[15];
    }
    __syncthreads();
    if (tid == 0) off[NN] = carry_s;
}

// ---- K4: fill CSR (src and tgt per slot) ----
__global__ __launch_bounds__(256) void fill_kernel(
    const int* __restrict__ tgt, const int* __restrict__ src,
    int* __restrict__ cursor, int* __restrict__ edge_src, int* __restrict__ edge_tgt)
{
    int e = blockIdx.x * 256 + threadIdx.x;
    if (e >= NE) return;
    int t = tgt[e];
    int pos = atomicAdd(cursor + t, 1);
    edge_src[pos] = src[e];
    edge_tgt[pos] = t;
}

// ---- K5: per-CSR-slot scores, all 8 heads per thread; probs = exp(sc/4).
// Head h spans dims 16h..16h+15 == float4 indices 4h..4h+3 of the 128-dim row.
// No max subtraction: scores are O(1) (|sc| < ~6), exp cannot overflow fp32;
// normalization in K6 makes the result mathematically identical to the reference.
__global__ __launch_bounds__(256) void score_kernel(
    const int* __restrict__ edge_src, const int* __restrict__ edge_tgt,
    const float* __restrict__ q, const float* __restrict__ k,
    float* __restrict__ probs)
{
    int p = blockIdx.x * 256 + threadIdx.x;
    if (p >= NE) return;
    int ss = edge_src[p], tt = edge_tgt[p];
    const float4* qp = (const float4*)(q + (size_t)ss * DIM);
    const float4* kp = (const float4*)(k + (size_t)tt * DIM);
    float pr[8];
#pragma unroll
    for (int h = 0; h < 8; ++h) {
        float sc = 0.f;
#pragma unroll
        for (int u = 0; u < 4; ++u) {
            float4 a = qp[4 * h + u];
            float4 b = kp[4 * h + u];
            sc += a.x * b.x + a.y * b.y + a.z * b.z + a.w * b.w;
        }
        pr[h] = __expf(sc * 0.25f);   // 1/sqrt(HD)
    }
    float4* op = (float4*)(probs + (size_t)p * NH);
    op[0] = make_float4(pr[0], pr[1], pr[2], pr[3]);
    op[1] = make_float4(pr[4], pr[5], pr[6], pr[7]);
}

// ---- K6: per-node aggregate. Wave per node.
// Phase 1: lane=(h,j) sums probs coalesced, shfl-reduce -> denom per head.
// Phase 2: lane owns dims {16h+2j, +1}; per edge: broadcast prob + coalesced v row.
__global__ __launch_bounds__(256) void agg_kernel(
    const int* __restrict__ off, const int* __restrict__ edge_src,
    const float* __restrict__ probs, const float* __restrict__ v,
    float* __restrict__ agg)
{
    const int node = blockIdx.x * 4 + (threadIdx.x >> 6);
    const int lane = threadIdx.x & 63;
    const int h = lane >> 3;
    const int j = lane & 7;
    const int dim = 16 * h + 2 * j;
    float* ap = agg + (size_t)node * DIM + dim;

    const int base = off[node];
    const int deg  = off[node + 1] - base;
    if (deg == 0) { *(float2*)ap = make_float2(0.f, 0.f); return; }

    // phase 1: denominator for head h
    float ssum = 0.f;
    for (int i = j; i < deg; i += 8)
        ssum += probs[(size_t)(base + i) * NH + h];
#pragma unroll
    for (int d = 1; d < 8; d <<= 1) ssum += __shfl_xor(ssum, d);
    float inv = 1.f / ssum;

    // phase 2: weighted sum of v rows
    float2 acc = make_float2(0.f, 0.f);
    for (int c0 = 0; c0 < deg; c0 += 64) {
        int cn = min(64, deg - c0);
        int srcv = edge_src[base + c0 + min(lane, cn - 1)];
        for (int i = 0; i < cn; ++i) {
            float pi = probs[(size_t)(base + c0 + i) * NH + h];
            int si = __shfl(srcv, i);
            float2 vv = *(const float2*)(v + (size_t)si * DIM + dim);
            acc.x += pi * vv.x;
            acc.y += pi * vv.y;
        }
    }
    *(float2*)ap = make_float2(acc.x * inv, acc.y * inv);
}

// ---- K7: out = agg @ Wo.T + bo (same structure as K1, one matrix) ----
__global__ __launch_bounds__(256) void outproj_kernel(
    const float* __restrict__ agg, const float* __restrict__ Wo,
    const float* __restrict__ bo, float* __restrict__ out)
{
    const int tid  = threadIdx.x;
    const int lane = tid & 63;
    const int colw = __builtin_amdgcn_readfirstlane((tid >> 6) & 1);
    const int roww = __builtin_amdgcn_readfirstlane(tid >> 7);
    const int j = colw * 64 + lane;
    const int rbase = blockIdx.x * 64 + roww * 32;

    float acc[32];
#pragma unroll
    for (int r = 0; r < 32; ++r) acc[r] = 0.f;

    const float* wop = Wo + (size_t)j * DIM;

    for (int k0 = 0; k0 < DIM; k0 += 16) {
        float4 wo4[4];
#pragma unroll
        for (int u = 0; u < 4; ++u) wo4[u] = ((const float4*)(wop + k0))[u];
#pragma unroll
        for (int r = 0; r < 32; ++r) {
            int row = rbase + r; if (row >= NN) row = NN - 1;
            const float4* xr = (const float4*)(agg + (size_t)row * DIM + k0);
            float4 xv[4];
#pragma unroll
            for (int u = 0; u < 4; ++u) xv[u] = xr[u];
            float a0 = acc[r];
#pragma unroll
            for (int u = 0; u < 4; ++u) {
                a0 += xv[u].x * wo4[u].x;
                a0 += xv[u].y * wo4[u].y;
                a0 += xv[u].z * wo4[u].z;
                a0 += xv[u].w * wo4[u].w;
            }
            acc[r] = a0;
        }
    }

    const float bias = bo[j];
#pragma unroll
    for (int r = 0; r < 32; ++r) {
        int row = rbase + r;
        if (row < NN) out[(size_t)row * DIM + j] = acc[r] + bias;
    }
}

extern "C" void kernel_launch(void* const* d_in, const int* in_sizes, int n_in,
                              void* d_out, int out_size, void* d_ws, size_t ws_size,
                              hipStream_t stream) {
    const float* x  = (const float*)d_in[0];
    const int*   ei = (const int*)d_in[1];      // [2, NE]: row0 = tgt, row1 = src
    const float* Wq = (const float*)d_in[2];
    const float* bq = (const float*)d_in[3];
    const float* Wk = (const float*)d_in[4];
    const float* bk = (const float*)d_in[5];
    const float* Wv = (const float*)d_in[6];
    const float* bv = (const float*)d_in[7];
    const float* Wo = (const float*)d_in[8];
    const float* bo = (const float*)d_in[9];

    const int* tgt = ei;
    const int* src = ei + NE;

    char* ws = (char*)d_ws;
    const size_t SZ_NODE = (size_t)NN * DIM * sizeof(float);   // 25.6 MB
    const size_t SZ_PROB = (size_t)NE * NH * sizeof(float);    // 25.6 MB

    float* q     = (float*)(ws);
    float* k     = (float*)(ws + SZ_NODE);
    float* v     = (float*)(ws + 2 * SZ_NODE);
    float* probs = (float*)(ws + 3 * SZ_NODE);
    float* agg   = k;   // k is dead after score_kernel; reuse as agg

    char* wi = ws + 3 * SZ_NODE + SZ_PROB;
    int* cnt      = (int*)(wi);
    int* off      = (int*)(wi + (size_t)NN * 4);
    int* cursor   = (int*)(wi + (size_t)(2 * NN + 1) * 4);
    int* edge_src = (int*)(wi + (size_t)(3 * NN + 1) * 4);
    int* edge_tgt = (int*)(wi + (size_t)(3 * NN + 1) * 4 + (size_t)NE * 4);

    const int gemm_blocks = (NN + 63) / 64;    // 782
    const int edge_blocks = (NE + 255) / 256;  // 3125

    hipMemsetAsync(cnt, 0, (size_t)NN * 4, stream);
    qkv_kernel<<<gemm_blocks, 256, 0, stream>>>(
        x, Wq, bq, Wk, bk, Wv, bv, q, k, v);
    hist_kernel<<<edge_blocks, 256, 0, stream>>>(tgt, cnt);
    scan_kernel<<<1, 1024, 0, stream>>>(cnt, off, cursor);
    fill_kernel<<<edge_blocks, 256, 0, stream>>>(tgt, src, cursor, edge_src, edge_tgt);
    score_kernel<<<edge_blocks, 256, 0, stream>>>(edge_src, edge_tgt, q, k, probs);
    agg_kernel<<<(NN + 3) / 4, 256, 0, stream>>>(off, edge_src, probs, v, agg);
    outproj_kernel<<<gemm_blocks, 256, 0, stream>>>(agg, Wo, bo, (float*)d_out);
}

// Round 5
// 376.623 us; speedup vs baseline: 2.0932x; 2.0932x over previous
//
#include <hip/hip_runtime.h>
#include <math.h>

#define NN 50000
#define NE 800000
#define DIM 128
#define NH 8
#define HD 16
#define NTILE 3125   // NN/16 exactly

typedef short v8s __attribute__((ext_vector_type(8)));
typedef float v4f __attribute__((ext_vector_type(4)));

__device__ __forceinline__ unsigned short f2b(float f) {
    unsigned u = __float_as_uint(f);
    u = (u + 0x7fffu + ((u >> 16) & 1u)) >> 16;   // round-to-nearest-even
    return (unsigned short)u;
}
__device__ __forceinline__ float blo(unsigned w) { return __uint_as_float(w << 16); }
__device__ __forceinline__ float bhi(unsigned w) { return __uint_as_float(w & 0xffff0000u); }

// ---- K0: convert x -> bf16, W{q,k,v,o} -> bf16 (packed), zero cnt ----
#define NX4 (NN * DIM / 4)          // 1,600,000 float4 of x
#define NW4 (4 * DIM * DIM / 4)     // 16,384 float4 of W
#define NC4 ((NN + 3) / 4)          // 12,500 int4 of cnt
__global__ __launch_bounds__(256) void convert_kernel(
    const float* __restrict__ x,
    const float* __restrict__ Wq, const float* __restrict__ Wk,
    const float* __restrict__ Wv, const float* __restrict__ Wo,
    unsigned short* __restrict__ xb, unsigned short* __restrict__ Wb,
    int* __restrict__ cnt)
{
    int i = blockIdx.x * 256 + threadIdx.x;
    if (i < NX4) {
        float4 f = ((const float4*)x)[i];
        uint2 o;
        o.x = (unsigned)f2b(f.x) | ((unsigned)f2b(f.y) << 16);
        o.y = (unsigned)f2b(f.z) | ((unsigned)f2b(f.w) << 16);
        ((uint2*)xb)[i] = o;
    } else if (i < NX4 + NW4) {
        int idx = i - NX4;
        int mat = idx >> 12;            // 4096 float4 per matrix
        int off = idx & 4095;
        const float* Wsrc = (mat == 0) ? Wq : (mat == 1) ? Wk : (mat == 2) ? Wv : Wo;
        float4 f = ((const float4*)Wsrc)[off];
        uint2 o;
        o.x = (unsigned)f2b(f.x) | ((unsigned)f2b(f.y) << 16);
        o.y = (unsigned)f2b(f.z) | ((unsigned)f2b(f.w) << 16);
        ((uint2*)(Wb + (size_t)mat * DIM * DIM))[off] = o;
    } else if (i < NX4 + NW4 + NC4) {
        int idx = i - NX4 - NW4;
        ((int4*)cnt)[idx] = make_int4(0, 0, 0, 0);
    }
}

// ---- K1: QKV projection via MFMA bf16. One wave per (row-tile, matrix). ----
// q[row][col] = sum_k x[row][k] * W[col][k]  (+ bias), output stored as bf16.
__global__ __launch_bounds__(256) void qkv_mfma_kernel(
    const unsigned short* __restrict__ xb, const unsigned short* __restrict__ Wb,
    const float* __restrict__ bq, const float* __restrict__ bk, const float* __restrict__ bv,
    unsigned short* __restrict__ qb, unsigned short* __restrict__ kb,
    unsigned short* __restrict__ vb)
{
    int w = blockIdx.x * 4 + (threadIdx.x >> 6);
    if (w >= 3 * NTILE) return;
    const int rt  = w % NTILE;
    const int mat = w / NTILE;
    const int lane = threadIdx.x & 63;
    const int m = lane & 15;
    const int quad = lane >> 4;

    const unsigned short* B = Wb + (size_t)mat * DIM * DIM;
    const float* bias_p = (mat == 0) ? bq : (mat == 1) ? bk : bv;
    unsigned short* outp = (mat == 0) ? qb : (mat == 1) ? kb : vb;

    const int r0 = rt * 16;
    // A fragments: rows r0+m, k = kt*32 + quad*8 + (0..7)
    v8s a[4];
#pragma unroll
    for (int kt = 0; kt < 4; ++kt)
        a[kt] = *(const v8s*)(xb + (size_t)(r0 + m) * DIM + kt * 32 + quad * 8);

#pragma unroll
    for (int nt = 0; nt < 8; ++nt) {
        v4f c = {0.f, 0.f, 0.f, 0.f};
#pragma unroll
        for (int kt = 0; kt < 4; ++kt) {
            v8s b = *(const v8s*)(B + (size_t)(nt * 16 + m) * DIM + kt * 32 + quad * 8);
            c = __builtin_amdgcn_mfma_f32_16x16x32_bf16(a[kt], b, c, 0, 0, 0);
        }
        int col = nt * 16 + m;           // C/D: col = lane&15
        float bias = bias_p[col];
#pragma unroll
        for (int i = 0; i < 4; ++i) {
            int row = r0 + quad * 4 + i; // C/D: row = quad*4 + reg
            outp[(size_t)row * DIM + col] = f2b(c[i] + bias);
        }
    }
}

// ---- K2: histogram of edges per target node ----
__global__ __launch_bounds__(256) void hist_kernel(
    const int* __restrict__ tgt, int* __restrict__ cnt)
{
    int e = blockIdx.x * 256 + threadIdx.x;
    if (e < NE) atomicAdd(cnt + tgt[e], 1);
}

// ---- K3: single-block exclusive scan, 4 elems/thread ----
__global__ __launch_bounds__(1024) void scan_kernel(
    const int* __restrict__ cnt, int* __restrict__ off, int* __restrict__ cursor)
{
    __shared__ int wsum[16];
    __shared__ int carry_s;
    const int tid = threadIdx.x;
    const int lane = tid & 63;
    const int wid = tid >> 6;
    if (tid == 0) carry_s = 0;
    __syncthreads();
    for (int base = 0; base < NN; base += 4096) {
        int i0 = base + tid * 4;
        int e0 = (i0 + 0 < NN) ? cnt[i0 + 0] : 0;
        int e1 = (i0 + 1 < NN) ? cnt[i0 + 1] : 0;
        int e2 = (i0 + 2 < NN) ? cnt[i0 + 2] : 0;
        int e3 = (i0 + 3 < NN) ? cnt[i0 + 3] : 0;
        int tsum = e0 + e1 + e2 + e3;
        int incl = tsum;
#pragma unroll
        for (int d = 1; d < 64; d <<= 1) {
            int t = __shfl_up(incl, d);
            if (lane >= d) incl += t;
        }
        if (lane == 63) wsum[wid] = incl;
        __syncthreads();
        if (wid == 0) {
            int wv = (lane < 16) ? wsum[lane] : 0;
#pragma unroll
            for (int d = 1; d < 16; d <<= 1) {
                int t = __shfl_up(wv, d);
                if (lane >= d) wv += t;
            }
            if (lane < 16) wsum[lane] = wv;
        }
        __syncthreads();
        int wave_excl = (wid == 0) ? 0 : wsum[wid - 1];
        int carry = carry_s;
        int excl = carry + wave_excl + (incl - tsum);
        if (i0 + 0 < NN) { off[i0 + 0] = excl;               cursor[i0 + 0] = excl; }
        if (i0 + 1 < NN) { off[i0 + 1] = excl + e0;          cursor[i0 + 1] = excl + e0; }
        if (i0 + 2 < NN) { off[i0 + 2] = excl + e0 + e1;     cursor[i0 + 2] = excl + e0 + e1; }
        if (i0 + 3 < NN) { off[i0 + 3] = excl + e0 + e1 + e2; cursor[i0 + 3] = excl + e0 + e1 + e2; }
        __syncthreads();
        if (tid == 1023) carry_s = carry + wsum[15];
    }
    __syncthreads();
    if (tid == 0) off[NN] = carry_s;
}

// ---- K4: fill CSR (src and tgt per slot) ----
__global__ __launch_bounds__(256) void fill_kernel(
    const int* __restrict__ tgt, const int* __restrict__ src,
    int* __restrict__ cursor, int* __restrict__ edge_src, int* __restrict__ edge_tgt)
{
    int e = blockIdx.x * 256 + threadIdx.x;
    if (e >= NE) return;
    int t = tgt[e];
    int pos = atomicAdd(cursor + t, 1);
    edge_src[pos] = src[e];
    edge_tgt[pos] = t;
}

// ---- K5: per-CSR-slot scores from bf16 q/k; probs = exp(sc/4), fp32.
// Head h spans bf16 dims 16h..16h+15 == uint4 words [2h], [2h+1] of the row.
__global__ __launch_bounds__(256) void score_kernel(
    const int* __restrict__ edge_src, const int* __restrict__ edge_tgt,
    const unsigned short* __restrict__ qb, const unsigned short* __restrict__ kb,
    float* __restrict__ probs)
{
    int p = blockIdx.x * 256 + threadIdx.x;
    if (p >= NE) return;
    int ss = edge_src[p], tt = edge_tgt[p];
    const uint4* qr = (const uint4*)(qb + (size_t)ss * DIM);
    const uint4* kr = (const uint4*)(kb + (size_t)tt * DIM);
    float pr[8];
#pragma unroll
    for (int h = 0; h < 8; ++h) {
        uint4 a0 = qr[2 * h], a1 = qr[2 * h + 1];
        uint4 b0 = kr[2 * h], b1 = kr[2 * h + 1];
        float sc = 0.f;
        sc += blo(a0.x) * blo(b0.x) + bhi(a0.x) * bhi(b0.x);
        sc += blo(a0.y) * blo(b0.y) + bhi(a0.y) * bhi(b0.y);
        sc += blo(a0.z) * blo(b0.z) + bhi(a0.z) * bhi(b0.z);
        sc += blo(a0.w) * blo(b0.w) + bhi(a0.w) * bhi(b0.w);
        sc += blo(a1.x) * blo(b1.x) + bhi(a1.x) * bhi(b1.x);
        sc += blo(a1.y) * blo(b1.y) + bhi(a1.y) * bhi(b1.y);
        sc += blo(a1.z) * blo(b1.z) + bhi(a1.z) * bhi(b1.z);
        sc += blo(a1.w) * blo(b1.w) + bhi(a1.w) * bhi(b1.w);
        pr[h] = __expf(sc * 0.25f);   // 1/sqrt(HD); |sc| is O(1), no overflow
    }
    float4* op = (float4*)(probs + (size_t)p * NH);
    op[0] = make_float4(pr[0], pr[1], pr[2], pr[3]);
    op[1] = make_float4(pr[4], pr[5], pr[6], pr[7]);
}

// ---- K6: per-node aggregate (wave per node), v in bf16, agg out in bf16 ----
__global__ __launch_bounds__(256) void agg_kernel(
    const int* __restrict__ off, const int* __restrict__ edge_src,
    const float* __restrict__ probs, const unsigned short* __restrict__ vb,
    unsigned short* __restrict__ aggb)
{
    const int node = blockIdx.x * 4 + (threadIdx.x >> 6);
    const int lane = threadIdx.x & 63;
    const int h = lane >> 3;
    const int j = lane & 7;
    const int dim = 16 * h + 2 * j;
    unsigned* ap = (unsigned*)(aggb + (size_t)node * DIM + dim);

    const int base = off[node];
    const int deg  = off[node + 1] - base;
    if (deg == 0) { *ap = 0u; return; }

    // phase 1: denominator for head h (coalesced prob reads + 8-lane reduce)
    float ssum = 0.f;
    for (int i = j; i < deg; i += 8)
        ssum += probs[(size_t)(base + i) * NH + h];
#pragma unroll
    for (int d = 1; d < 8; d <<= 1) ssum += __shfl_xor(ssum, d);
    float inv = 1.f / ssum;

    // phase 2: weighted sum of v rows; lane reads packed bf16 pair (coalesced)
    float ax = 0.f, ay = 0.f;
    for (int c0 = 0; c0 < deg; c0 += 64) {
        int cn = min(64, deg - c0);
        int srcv = edge_src[base + c0 + min(lane, cn - 1)];
        for (int i = 0; i < cn; ++i) {
            float pi = probs[(size_t)(base + c0 + i) * NH + h];
            int si = __shfl(srcv, i);
            unsigned wv = *(const unsigned*)(vb + (size_t)si * DIM + dim);
            ax += pi * blo(wv);
            ay += pi * bhi(wv);
        }
    }
    *ap = (unsigned)f2b(ax * inv) | ((unsigned)f2b(ay * inv) << 16);
}

// ---- K7: out = agg @ Wo.T + bo via MFMA, fp32 output ----
__global__ __launch_bounds__(256) void outproj_mfma_kernel(
    const unsigned short* __restrict__ aggb, const unsigned short* __restrict__ Wob,
    const float* __restrict__ bo, float* __restrict__ out)
{
    int w = blockIdx.x * 4 + (threadIdx.x >> 6);
    if (w >= NTILE) return;
    const int rt = w;
    const int lane = threadIdx.x & 63;
    const int m = lane & 15;
    const int quad = lane >> 4;
    const int r0 = rt * 16;

    v8s a[4];
#pragma unroll
    for (int kt = 0; kt < 4; ++kt)
        a[kt] = *(const v8s*)(aggb + (size_t)(r0 + m) * DIM + kt * 32 + quad * 8);

#pragma unroll
    for (int nt = 0; nt < 8; ++nt) {
        v4f c = {0.f, 0.f, 0.f, 0.f};
#pragma unroll
        for (int kt = 0; kt < 4; ++kt) {
            v8s b = *(const v8s*)(Wob + (size_t)(nt * 16 + m) * DIM + kt * 32 + quad * 8);
            c = __builtin_amdgcn_mfma_f32_16x16x32_bf16(a[kt], b, c, 0, 0, 0);
        }
        int col = nt * 16 + m;
        float bias = bo[col];
#pragma unroll
        for (int i = 0; i < 4; ++i) {
            int row = r0 + quad * 4 + i;
            out[(size_t)row * DIM + col] = c[i] + bias;
        }
    }
}

extern "C" void kernel_launch(void* const* d_in, const int* in_sizes, int n_in,
                              void* d_out, int out_size, void* d_ws, size_t ws_size,
                              hipStream_t stream) {
    const float* x  = (const float*)d_in[0];
    const int*   ei = (const int*)d_in[1];      // [2, NE]: row0 = tgt, row1 = src
    const float* Wq = (const float*)d_in[2];
    const float* bq = (const float*)d_in[3];
    const float* Wk = (const float*)d_in[4];
    const float* bk = (const float*)d_in[5];
    const float* Wv = (const float*)d_in[6];
    const float* bv = (const float*)d_in[7];
    const float* Wo = (const float*)d_in[8];
    const float* bo = (const float*)d_in[9];

    const int* tgt = ei;
    const int* src = ei + NE;

    char* ws = (char*)d_ws;
    const size_t SZ_BF   = (size_t)NN * DIM * 2;      // 12.8 MB (bf16 node array)
    const size_t SZ_PROB = (size_t)NE * NH * 4;       // 25.6 MB

    unsigned short* xb   = (unsigned short*)(ws);
    unsigned short* qb   = (unsigned short*)(ws + SZ_BF);
    unsigned short* kb   = (unsigned short*)(ws + 2 * SZ_BF);
    unsigned short* vb   = (unsigned short*)(ws + 3 * SZ_BF);
    unsigned short* aggb = (unsigned short*)(ws + 4 * SZ_BF);
    unsigned short* Wb   = (unsigned short*)(ws + 5 * SZ_BF);   // 4 mats packed, 128 KB
    float* probs         = (float*)(ws + 5 * SZ_BF + (size_t)4 * DIM * DIM * 2);

    char* wi = ws + 5 * SZ_BF + (size_t)4 * DIM * DIM * 2 + SZ_PROB;
    int* cnt      = (int*)(wi);
    int* off      = (int*)(wi + (size_t)NN * 4);
    int* cursor   = (int*)(wi + (size_t)(2 * NN + 1) * 4);
    int* edge_src = (int*)(wi + (size_t)(3 * NN + 1) * 4);
    int* edge_tgt = (int*)(wi + (size_t)(3 * NN + 1) * 4 + (size_t)NE * 4);

    const int conv_blocks = (NX4 + NW4 + NC4 + 255) / 256;
    const int edge_blocks = (NE + 255) / 256;  // 3125

    convert_kernel<<<conv_blocks, 256, 0, stream>>>(x, Wq, Wk, Wv, Wo, xb, Wb, cnt);
    qkv_mfma_kernel<<<(3 * NTILE + 3) / 4, 256, 0, stream>>>(
        xb, Wb, bq, bk, bv, qb, kb, vb);
    hist_kernel<<<edge_blocks, 256, 0, stream>>>(tgt, cnt);
    scan_kernel<<<1, 1024, 0, stream>>>(cnt, off, cursor);
    fill_kernel<<<edge_blocks, 256, 0, stream>>>(tgt, src, cursor, edge_src, edge_tgt);
    score_kernel<<<edge_blocks, 256, 0, stream>>>(edge_src, edge_tgt, qb, kb, probs);
    agg_kernel<<<(NN + 3) / 4, 256, 0, stream>>>(off, edge_src, probs, vb, aggb);
    outproj_mfma_kernel<<<(NTILE + 3) / 4, 256, 0, stream>>>(
        aggb, Wb + (size_t)3 * DIM * DIM, bo, (float*)d_out);
}

// Round 6
// 310.052 us; speedup vs baseline: 2.5426x; 1.2147x over previous
//
#include <hip/hip_runtime.h>
#include <math.h>

#define NN 50000
#define NE 800000
#define DIM 128
#define NH 8
#define HD 16
#define NTILE 3125            // NN/16 exactly
#define TPB 782               // ceil(NTILE/4) tile-groups per matrix
#define LROW 136              // LDS row stride in shorts (128 + 8 pad)

typedef short v8s __attribute__((ext_vector_type(8)));
typedef float v4f __attribute__((ext_vector_type(4)));

__device__ __forceinline__ unsigned short f2b(float f) {
    unsigned u = __float_as_uint(f);
    u = (u + 0x7fffu + ((u >> 16) & 1u)) >> 16;   // round-to-nearest-even
    return (unsigned short)u;
}
__device__ __forceinline__ float blo(unsigned w) { return __uint_as_float(w << 16); }
__device__ __forceinline__ float bhi(unsigned w) { return __uint_as_float(w & 0xffff0000u); }

// ---- K0: convert W{q,k,v,o} -> bf16 packed; zero cnt ----
#define NW4 (4 * DIM * DIM / 4)     // 16384 float4 of W
#define NC4 ((NN + 3) / 4)          // 12500 int4 of cnt
__global__ __launch_bounds__(256) void convert_kernel(
    const float* __restrict__ Wq, const float* __restrict__ Wk,
    const float* __restrict__ Wv, const float* __restrict__ Wo,
    unsigned short* __restrict__ Wb, int* __restrict__ cnt)
{
    int i = blockIdx.x * 256 + threadIdx.x;
    if (i < NW4) {
        int mat = i >> 12;            // 4096 float4 per matrix
        int off = i & 4095;
        const float* Wsrc = (mat == 0) ? Wq : (mat == 1) ? Wk : (mat == 2) ? Wv : Wo;
        float4 f = ((const float4*)Wsrc)[off];
        uint2 o;
        o.x = (unsigned)f2b(f.x) | ((unsigned)f2b(f.y) << 16);
        o.y = (unsigned)f2b(f.z) | ((unsigned)f2b(f.w) << 16);
        ((uint2*)(Wb + (size_t)mat * DIM * DIM))[off] = o;
    } else if (i < NW4 + NC4) {
        ((int4*)cnt)[i - NW4] = make_int4(0, 0, 0, 0);
    }
}

// ---- K1: QKV via MFMA. W staged in LDS (padded); x read fp32, converted in-reg.
// Block: 4 waves, 4 row-tiles of one matrix. grid.x = 3*TPB (mat-major).
__global__ __launch_bounds__(256) void qkv_mfma_kernel(
    const float* __restrict__ x, const unsigned short* __restrict__ Wb,
    const float* __restrict__ bq, const float* __restrict__ bk, const float* __restrict__ bv,
    unsigned short* __restrict__ qb, unsigned short* __restrict__ kb,
    unsigned short* __restrict__ vb)
{
    __shared__ unsigned short Wl[DIM * LROW];   // 34816 B
    const int mat = blockIdx.x / TPB;
    const int tg  = blockIdx.x % TPB;
    const int tid = threadIdx.x;
    const int lane = tid & 63;
    const int warp = tid >> 6;
    const int m = lane & 15;
    const int quad = lane >> 4;

    // stage this matrix into LDS: 2048 uint4 chunks (8 shorts each)
    const unsigned short* Wg = Wb + (size_t)mat * DIM * DIM;
#pragma unroll
    for (int it = 0; it < 8; ++it) {
        int chunk = it * 256 + tid;           // 0..2047
        int row = chunk >> 4, c8 = chunk & 15;
        *(uint4*)(Wl + row * LROW + c8 * 8) = ((const uint4*)Wg)[chunk];
    }
    __syncthreads();

    const int rt = tg * 4 + warp;
    if (rt >= NTILE) return;
    const int r0 = rt * 16;

    const float* bias_p = (mat == 0) ? bq : (mat == 1) ? bk : bv;
    unsigned short* outp = (mat == 0) ? qb : (mat == 1) ? kb : vb;

    // A fragments: row r0+m, k = kt*32 + quad*8 + (0..7); fp32 -> bf16 in reg
    v8s a[4];
#pragma unroll
    for (int kt = 0; kt < 4; ++kt) {
        const float4* xr = (const float4*)(x + (size_t)(r0 + m) * DIM + kt * 32 + quad * 8);
        float4 f0 = xr[0], f1 = xr[1];
        v8s t;
        t[0] = (short)f2b(f0.x); t[1] = (short)f2b(f0.y);
        t[2] = (short)f2b(f0.z); t[3] = (short)f2b(f0.w);
        t[4] = (short)f2b(f1.x); t[5] = (short)f2b(f1.y);
        t[6] = (short)f2b(f1.z); t[7] = (short)f2b(f1.w);
        a[kt] = t;
    }

#pragma unroll
    for (int nt = 0; nt < 8; ++nt) {
        v4f c = {0.f, 0.f, 0.f, 0.f};
#pragma unroll
        for (int kt = 0; kt < 4; ++kt) {
            v8s b = *(const v8s*)(Wl + (nt * 16 + m) * LROW + kt * 32 + quad * 8);
            c = __builtin_amdgcn_mfma_f32_16x16x32_bf16(a[kt], b, c, 0, 0, 0);
        }
        int col = nt * 16 + m;           // C/D: col = lane&15
        float bias = bias_p[col];
#pragma unroll
        for (int i = 0; i < 4; ++i) {
            int row = r0 + quad * 4 + i; // C/D: row = quad*4 + reg
            outp[(size_t)row * DIM + col] = f2b(c[i] + bias);
        }
    }
}

// ---- K2: histogram of edges per target node ----
__global__ __launch_bounds__(256) void hist_kernel(
    const int* __restrict__ tgt, int* __restrict__ cnt)
{
    int e = blockIdx.x * 256 + threadIdx.x;
    if (e < NE) atomicAdd(cnt + tgt[e], 1);
}

// ---- K3: single-block exclusive scan, 4 elems/thread ----
__global__ __launch_bounds__(1024) void scan_kernel(
    const int* __restrict__ cnt, int* __restrict__ off, int* __restrict__ cursor)
{
    __shared__ int wsum[16];
    __shared__ int carry_s;
    const int tid = threadIdx.x;
    const int lane = tid & 63;
    const int wid = tid >> 6;
    if (tid == 0) carry_s = 0;
    __syncthreads();
    for (int base = 0; base < NN; base += 4096) {
        int i0 = base + tid * 4;
        int e0 = (i0 + 0 < NN) ? cnt[i0 + 0] : 0;
        int e1 = (i0 + 1 < NN) ? cnt[i0 + 1] : 0;
        int e2 = (i0 + 2 < NN) ? cnt[i0 + 2] : 0;
        int e3 = (i0 + 3 < NN) ? cnt[i0 + 3] : 0;
        int tsum = e0 + e1 + e2 + e3;
        int incl = tsum;
#pragma unroll
        for (int d = 1; d < 64; d <<= 1) {
            int t = __shfl_up(incl, d);
            if (lane >= d) incl += t;
        }
        if (lane == 63) wsum[wid] = incl;
        __syncthreads();
        if (wid == 0) {
            int wv = (lane < 16) ? wsum[lane] : 0;
#pragma unroll
            for (int d = 1; d < 16; d <<= 1) {
                int t = __shfl_up(wv, d);
                if (lane >= d) wv += t;
            }
            if (lane < 16) wsum[lane] = wv;
        }
        __syncthreads();
        int wave_excl = (wid == 0) ? 0 : wsum[wid - 1];
        int carry = carry_s;
        int excl = carry + wave_excl + (incl - tsum);
        if (i0 + 0 < NN) { off[i0 + 0] = excl;                cursor[i0 + 0] = excl; }
        if (i0 + 1 < NN) { off[i0 + 1] = excl + e0;           cursor[i0 + 1] = excl + e0; }
        if (i0 + 2 < NN) { off[i0 + 2] = excl + e0 + e1;      cursor[i0 + 2] = excl + e0 + e1; }
        if (i0 + 3 < NN) { off[i0 + 3] = excl + e0 + e1 + e2; cursor[i0 + 3] = excl + e0 + e1 + e2; }
        __syncthreads();
        if (tid == 1023) carry_s = carry + wsum[15];
    }
    __syncthreads();
    if (tid == 0) off[NN] = carry_s;
}

// ---- K4: fill CSR (src only; tgt implicit in bucket) ----
__global__ __launch_bounds__(256) void fill_kernel(
    const int* __restrict__ tgt, const int* __restrict__ src,
    int* __restrict__ cursor, int* __restrict__ edge_src)
{
    int e = blockIdx.x * 256 + threadIdx.x;
    if (e >= NE) return;
    int t = tgt[e];
    int pos = atomicAdd(cursor + t, 1);
    edge_src[pos] = src[e];
}

// ---- K5: fused attention (score + softmax + aggregate), wave per node.
// lane = h*8+j owns dims {16h+2j, 16h+2j+1}. No max-subtraction: |sc| = O(1)
// so exp is safe in fp32; final normalization matches the reference exactly.
__global__ __launch_bounds__(256) void attn_kernel(
    const int* __restrict__ off, const int* __restrict__ edge_src,
    const unsigned short* __restrict__ qb, const unsigned short* __restrict__ kb,
    const unsigned short* __restrict__ vb, unsigned short* __restrict__ aggb)
{
    const int node = blockIdx.x * 4 + (threadIdx.x >> 6);
    const int lane = threadIdx.x & 63;
    const int h = lane >> 3;
    const int j = lane & 7;
    const int dim = 16 * h + 2 * j;
    unsigned* ap = (unsigned*)(aggb + (size_t)node * DIM + dim);

    const int base = off[node];
    const int deg  = off[node + 1] - base;
    if (deg == 0) { *ap = 0u; return; }

    // this node's k pair (the dot's k side is k[tgt] = own node)
    unsigned kw = *(const unsigned*)(kb + (size_t)node * DIM + dim);
    const float klo = blo(kw), khi = bhi(kw);

    float ax = 0.f, ay = 0.f, ssum = 0.f;
    for (int c0 = 0; c0 < deg; c0 += 64) {
        int cn = min(64, deg - c0);
        int srcv = edge_src[base + c0 + min(lane, cn - 1)];
        for (int i = 0; i < cn; ++i) {
            int si = __shfl(srcv, i);
            unsigned qw = *(const unsigned*)(qb + (size_t)si * DIM + dim);
            float part = blo(qw) * klo + bhi(qw) * khi;
            // reduce over the 8 lanes of this head (j = 0..7)
            part += __shfl_xor(part, 1);
            part += __shfl_xor(part, 2);
            part += __shfl_xor(part, 4);
            float p = __expf(part * 0.25f);   // 1/sqrt(HD)
            unsigned vw = *(const unsigned*)(vb + (size_t)si * DIM + dim);
            ax += p * blo(vw);
            ay += p * bhi(vw);
            ssum += p;
        }
    }
    float inv = 1.f / ssum;
    *ap = (unsigned)f2b(ax * inv) | ((unsigned)f2b(ay * inv) << 16);
}

// ---- K6: out = agg @ Wo.T + bo via MFMA, Wo staged in LDS, fp32 out ----
__global__ __launch_bounds__(256) void outproj_mfma_kernel(
    const unsigned short* __restrict__ aggb, const unsigned short* __restrict__ Wob,
    const float* __restrict__ bo, float* __restrict__ out)
{
    __shared__ unsigned short Wl[DIM * LROW];
    const int tid = threadIdx.x;
    const int lane = tid & 63;
    const int warp = tid >> 6;
    const int m = lane & 15;
    const int quad = lane >> 4;

#pragma unroll
    for (int it = 0; it < 8; ++it) {
        int chunk = it * 256 + tid;
        int row = chunk >> 4, c8 = chunk & 15;
        *(uint4*)(Wl + row * LROW + c8 * 8) = ((const uint4*)Wob)[chunk];
    }
    __syncthreads();

    const int rt = blockIdx.x * 4 + warp;
    if (rt >= NTILE) return;
    const int r0 = rt * 16;

    v8s a[4];
#pragma unroll
    for (int kt = 0; kt < 4; ++kt)
        a[kt] = *(const v8s*)(aggb + (size_t)(r0 + m) * DIM + kt * 32 + quad * 8);

#pragma unroll
    for (int nt = 0; nt < 8; ++nt) {
        v4f c = {0.f, 0.f, 0.f, 0.f};
#pragma unroll
        for (int kt = 0; kt < 4; ++kt) {
            v8s b = *(const v8s*)(Wl + (nt * 16 + m) * LROW + kt * 32 + quad * 8);
            c = __builtin_amdgcn_mfma_f32_16x16x32_bf16(a[kt], b, c, 0, 0, 0);
        }
        int col = nt * 16 + m;
        float bias = bo[col];
#pragma unroll
        for (int i = 0; i < 4; ++i) {
            int row = r0 + quad * 4 + i;
            out[(size_t)row * DIM + col] = c[i] + bias;
        }
    }
}

extern "C" void kernel_launch(void* const* d_in, const int* in_sizes, int n_in,
                              void* d_out, int out_size, void* d_ws, size_t ws_size,
                              hipStream_t stream) {
    const float* x  = (const float*)d_in[0];
    const int*   ei = (const int*)d_in[1];      // [2, NE]: row0 = tgt, row1 = src
    const float* Wq = (const float*)d_in[2];
    const float* bq = (const float*)d_in[3];
    const float* Wk = (const float*)d_in[4];
    const float* bk = (const float*)d_in[5];
    const float* Wv = (const float*)d_in[6];
    const float* bv = (const float*)d_in[7];
    const float* Wo = (const float*)d_in[8];
    const float* bo = (const float*)d_in[9];

    const int* tgt = ei;
    const int* src = ei + NE;

    char* ws = (char*)d_ws;
    const size_t SZ_BF = (size_t)NN * DIM * 2;      // 12.8 MB per bf16 node array

    unsigned short* qb   = (unsigned short*)(ws);
    unsigned short* kb   = (unsigned short*)(ws + SZ_BF);
    unsigned short* vb   = (unsigned short*)(ws + 2 * SZ_BF);
    unsigned short* aggb = (unsigned short*)(ws + 3 * SZ_BF);
    unsigned short* Wb   = (unsigned short*)(ws + 4 * SZ_BF);   // 4 mats, 128 KB

    char* wi = ws + 4 * SZ_BF + (size_t)4 * DIM * DIM * 2;
    int* cnt      = (int*)(wi);
    int* off      = (int*)(wi + (size_t)NN * 4);
    int* cursor   = (int*)(wi + (size_t)(2 * NN + 1) * 4);
    int* edge_src = (int*)(wi + (size_t)(3 * NN + 1) * 4);

    const int conv_blocks = (NW4 + NC4 + 255) / 256;
    const int edge_blocks = (NE + 255) / 256;  // 3125

    convert_kernel<<<conv_blocks, 256, 0, stream>>>(Wq, Wk, Wv, Wo, Wb, cnt);
    qkv_mfma_kernel<<<3 * TPB, 256, 0, stream>>>(
        x, Wb, bq, bk, bv, qb, kb, vb);
    hist_kernel<<<edge_blocks, 256, 0, stream>>>(tgt, cnt);
    scan_kernel<<<1, 1024, 0, stream>>>(cnt, off, cursor);
    fill_kernel<<<edge_blocks, 256, 0, stream>>>(tgt, src, cursor, edge_src);
    attn_kernel<<<(NN + 3) / 4, 256, 0, stream>>>(off, edge_src, qb, kb, vb, aggb);
    outproj_mfma_kernel<<<TPB, 256, 0, stream>>>(
        aggb, Wb + (size_t)3 * DIM * DIM, bo, (float*)d_out);
}

// Round 7
// 288.825 us; speedup vs baseline: 2.7294x; 1.0735x over previous
//
#include <hip/hip_runtime.h>
#include <math.h>

#define NN 50000
#define NE 800000
#define DIM 128
#define NH 8
#define HD 16
#define NTILE 3125            // NN/16 exactly
#define TPB 782               // ceil(NTILE/4) tile-groups per matrix
#define LROW 136              // LDS row stride in shorts (128 + 8 pad)
#define QVROW 256             // interleaved qv row: 256 shorts = 512 B
#define SCAN_B 196            // ceil(NN/256)

typedef short v8s __attribute__((ext_vector_type(8)));
typedef float v4f __attribute__((ext_vector_type(4)));

__device__ __forceinline__ unsigned short f2b(float f) {
    unsigned u = __float_as_uint(f);
    u = (u + 0x7fffu + ((u >> 16) & 1u)) >> 16;   // round-to-nearest-even
    return (unsigned short)u;
}
__device__ __forceinline__ float blo(unsigned w) { return __uint_as_float(w << 16); }
__device__ __forceinline__ float bhi(unsigned w) { return __uint_as_float(w & 0xffff0000u); }

// ---- K0: convert W{q,k,v,o} -> bf16 packed; zero cnt ----
#define NW4 (4 * DIM * DIM / 4)     // 16384 float4 of W
#define NC4 ((NN + 3) / 4)          // 12500 int4 of cnt
__global__ __launch_bounds__(256) void convert_kernel(
    const float* __restrict__ Wq, const float* __restrict__ Wk,
    const float* __restrict__ Wv, const float* __restrict__ Wo,
    unsigned short* __restrict__ Wb, int* __restrict__ cnt)
{
    int i = blockIdx.x * 256 + threadIdx.x;
    if (i < NW4) {
        int mat = i >> 12;            // 4096 float4 per matrix
        int off = i & 4095;
        const float* Wsrc = (mat == 0) ? Wq : (mat == 1) ? Wk : (mat == 2) ? Wv : Wo;
        float4 f = ((const float4*)Wsrc)[off];
        uint2 o;
        o.x = (unsigned)f2b(f.x) | ((unsigned)f2b(f.y) << 16);
        o.y = (unsigned)f2b(f.z) | ((unsigned)f2b(f.w) << 16);
        ((uint2*)(Wb + (size_t)mat * DIM * DIM))[off] = o;
    } else if (i < NW4 + NC4) {
        ((int4*)cnt)[i - NW4] = make_int4(0, 0, 0, 0);
    }
}

// ---- K1: QKV via MFMA. W staged in LDS; x read fp32, converted in-reg.
// Outputs: q,v interleaved per-dim-pair into qvb (row = 256 shorts:
// [j2*4+0,1]=q pair, [j2*4+2,3]=v pair); k into kb.
__global__ __launch_bounds__(256) void qkv_mfma_kernel(
    const float* __restrict__ x, const unsigned short* __restrict__ Wb,
    const float* __restrict__ bq, const float* __restrict__ bk, const float* __restrict__ bv,
    unsigned short* __restrict__ qvb, unsigned short* __restrict__ kb)
{
    __shared__ unsigned short Wl[DIM * LROW];   // 34816 B
    const int mat = blockIdx.x / TPB;           // 0=q, 1=k, 2=v
    const int tg  = blockIdx.x % TPB;
    const int tid = threadIdx.x;
    const int lane = tid & 63;
    const int warp = tid >> 6;
    const int m = lane & 15;
    const int quad = lane >> 4;

    const unsigned short* Wg = Wb + (size_t)mat * DIM * DIM;
#pragma unroll
    for (int it = 0; it < 8; ++it) {
        int chunk = it * 256 + tid;           // 0..2047
        int row = chunk >> 4, c8 = chunk & 15;
        *(uint4*)(Wl + row * LROW + c8 * 8) = ((const uint4*)Wg)[chunk];
    }
    __syncthreads();

    const int rt = tg * 4 + warp;
    if (rt >= NTILE) return;
    const int r0 = rt * 16;

    const float* bias_p = (mat == 0) ? bq : (mat == 1) ? bk : bv;

    v8s a[4];
#pragma unroll
    for (int kt = 0; kt < 4; ++kt) {
        const float4* xr = (const float4*)(x + (size_t)(r0 + m) * DIM + kt * 32 + quad * 8);
        float4 f0 = xr[0], f1 = xr[1];
        v8s t;
        t[0] = (short)f2b(f0.x); t[1] = (short)f2b(f0.y);
        t[2] = (short)f2b(f0.z); t[3] = (short)f2b(f0.w);
        t[4] = (short)f2b(f1.x); t[5] = (short)f2b(f1.y);
        t[6] = (short)f2b(f1.z); t[7] = (short)f2b(f1.w);
        a[kt] = t;
    }

#pragma unroll
    for (int nt = 0; nt < 8; ++nt) {
        v4f c = {0.f, 0.f, 0.f, 0.f};
#pragma unroll
        for (int kt = 0; kt < 4; ++kt) {
            v8s b = *(const v8s*)(Wl + (nt * 16 + m) * LROW + kt * 32 + quad * 8);
            c = __builtin_amdgcn_mfma_f32_16x16x32_bf16(a[kt], b, c, 0, 0, 0);
        }
        int col = nt * 16 + m;           // C/D: col = lane&15
        float bias = bias_p[col];
#pragma unroll
        for (int i = 0; i < 4; ++i) {
            int row = r0 + quad * 4 + i; // C/D: row = quad*4 + reg
            unsigned short val = f2b(c[i] + bias);
            if (mat == 1) {
                kb[(size_t)row * DIM + col] = val;
            } else {
                // q at sub-offset 0/1, v at 2/3 within the dim-pair group
                int pos = (col >> 1) * 4 + (col & 1) + ((mat == 2) ? 2 : 0);
                qvb[(size_t)row * QVROW + pos] = val;
            }
        }
    }
}

// ---- K2: histogram of edges per target node ----
__global__ __launch_bounds__(256) void hist_kernel(
    const int* __restrict__ tgt, int* __restrict__ cnt)
{
    int e = blockIdx.x * 256 + threadIdx.x;
    if (e < NE) atomicAdd(cnt + tgt[e], 1);
}

// ---- K3a: per-block (256-elem) local exclusive scan + block sums ----
__global__ __launch_bounds__(256) void scan1_kernel(
    const int* __restrict__ cnt, int* __restrict__ off, int* __restrict__ bsum)
{
    __shared__ int ws4[4];
    const int tid = threadIdx.x, lane = tid & 63, wid = tid >> 6;
    int i = blockIdx.x * 256 + tid;
    int v0 = (i < NN) ? cnt[i] : 0;
    int incl = v0;
#pragma unroll
    for (int d = 1; d < 64; d <<= 1) {
        int t = __shfl_up(incl, d);
        if (lane >= d) incl += t;
    }
    if (lane == 63) ws4[wid] = incl;
    __syncthreads();
    int wexcl = 0;
#pragma unroll
    for (int t = 0; t < 3; ++t) if (t < wid) wexcl += ws4[t];
    if (i < NN) off[i] = wexcl + incl - v0;
    if (tid == 255) bsum[blockIdx.x] = wexcl + incl;
}

// ---- K3b: single-block scan of the 196 block sums; writes off[NN]=total ----
__global__ __launch_bounds__(256) void scan2_kernel(
    int* __restrict__ bsum, int* __restrict__ off)
{
    __shared__ int ws4[4];
    const int tid = threadIdx.x, lane = tid & 63, wid = tid >> 6;
    int v0 = (tid < SCAN_B) ? bsum[tid] : 0;
    int incl = v0;
#pragma unroll
    for (int d = 1; d < 64; d <<= 1) {
        int t = __shfl_up(incl, d);
        if (lane >= d) incl += t;
    }
    if (lane == 63) ws4[wid] = incl;
    __syncthreads();
    int wexcl = 0;
#pragma unroll
    for (int t = 0; t < 3; ++t) if (t < wid) wexcl += ws4[t];
    int excl = wexcl + incl - v0;
    if (tid < SCAN_B) bsum[tid] = excl;
    if (tid == SCAN_B - 1) off[NN] = excl + v0;   // grand total
}

// ---- K3c: add block base; also init cursor ----
__global__ __launch_bounds__(256) void scan3_kernel(
    int* __restrict__ off, const int* __restrict__ bsum, int* __restrict__ cursor)
{
    int i = blockIdx.x * 256 + threadIdx.x;
    if (i < NN) {
        int t = off[i] + bsum[blockIdx.x];
        off[i] = t;
        cursor[i] = t;
    }
}

// ---- K4: fill CSR (src only; tgt implicit in bucket) ----
__global__ __launch_bounds__(256) void fill_kernel(
    const int* __restrict__ tgt, const int* __restrict__ src,
    int* __restrict__ cursor, int* __restrict__ edge_src)
{
    int e = blockIdx.x * 256 + threadIdx.x;
    if (e >= NE) return;
    int t = tgt[e];
    int pos = atomicAdd(cursor + t, 1);
    edge_src[pos] = src[e];
}

// ---- K5: fused attention, 2 waves per node (even/odd edges), LDS combine.
// lane owns dims {2*lane, 2*lane+1} (head h = lane>>3 spans lanes 8h..8h+7).
// Per edge: ONE dwordx2 gather {q pair, v pair}; 8-lane dot reduce; exp; FMA.
// No max-subtraction: |score| = O(1) in fp32, normalization matches reference.
__global__ __launch_bounds__(256) void attn_kernel(
    const int* __restrict__ off, const int* __restrict__ edge_src,
    const unsigned short* __restrict__ qvb, const unsigned short* __restrict__ kb,
    unsigned short* __restrict__ aggb)
{
    __shared__ float red[2][64][3];
    const int tid = threadIdx.x;
    const int nib = tid >> 7;            // node-in-block (0..1)
    const int w   = (tid >> 6) & 1;      // wave half: even/odd edges
    const int lane = tid & 63;
    const int node = blockIdx.x * 2 + nib;

    const int base = off[node];
    const int deg  = off[node + 1] - base;

    unsigned kw = *(const unsigned*)(kb + (size_t)node * DIM + 2 * lane);
    const float klo = blo(kw), khi = bhi(kw);

    float ax = 0.f, ay = 0.f, ss = 0.f;
    for (int c0 = 0; c0 < deg; c0 += 128) {
        int lim = min(deg - c0, 128);
        int srcv = edge_src[base + min(c0 + 2 * lane + w, deg - 1)];
        int n_i = (lim + 1 - w) >> 1;
        for (int i = 0; i < n_i; ++i) {
            int si = __shfl(srcv, i);
            uint2 qv = *(const uint2*)(qvb + (size_t)si * QVROW + 4 * lane);
            float part = blo(qv.x) * klo + bhi(qv.x) * khi;
            part += __shfl_xor(part, 1);
            part += __shfl_xor(part, 2);
            part += __shfl_xor(part, 4);
            float p = __expf(part * 0.25f);   // 1/sqrt(HD)
            ax += p * blo(qv.y);
            ay += p * bhi(qv.y);
            ss += p;
        }
    }
    if (w == 1) {
        red[nib][lane][0] = ax; red[nib][lane][1] = ay; red[nib][lane][2] = ss;
    }
    __syncthreads();
    if (w == 0) {
        ax += red[nib][lane][0]; ay += red[nib][lane][1]; ss += red[nib][lane][2];
        unsigned* ap = (unsigned*)(aggb + (size_t)node * DIM + 2 * lane);
        if (deg == 0) {
            *ap = 0u;
        } else {
            float inv = 1.f / ss;
            *ap = (unsigned)f2b(ax * inv) | ((unsigned)f2b(ay * inv) << 16);
        }
    }
}

// ---- K6: out = agg @ Wo.T + bo via MFMA, Wo staged in LDS, fp32 out ----
__global__ __launch_bounds__(256) void outproj_mfma_kernel(
    const unsigned short* __restrict__ aggb, const unsigned short* __restrict__ Wob,
    const float* __restrict__ bo, float* __restrict__ out)
{
    __shared__ unsigned short Wl[DIM * LROW];
    const int tid = threadIdx.x;
    const int lane = tid & 63;
    const int warp = tid >> 6;
    const int m = lane & 15;
    const int quad = lane >> 4;

#pragma unroll
    for (int it = 0; it < 8; ++it) {
        int chunk = it * 256 + tid;
        int row = chunk >> 4, c8 = chunk & 15;
        *(uint4*)(Wl + row * LROW + c8 * 8) = ((const uint4*)Wob)[chunk];
    }
    __syncthreads();

    const int rt = blockIdx.x * 4 + warp;
    if (rt >= NTILE) return;
    const int r0 = rt * 16;

    v8s a[4];
#pragma unroll
    for (int kt = 0; kt < 4; ++kt)
        a[kt] = *(const v8s*)(aggb + (size_t)(r0 + m) * DIM + kt * 32 + quad * 8);

#pragma unroll
    for (int nt = 0; nt < 8; ++nt) {
        v4f c = {0.f, 0.f, 0.f, 0.f};
#pragma unroll
        for (int kt = 0; kt < 4; ++kt) {
            v8s b = *(const v8s*)(Wl + (nt * 16 + m) * LROW + kt * 32 + quad * 8);
            c = __builtin_amdgcn_mfma_f32_16x16x32_bf16(a[kt], b, c, 0, 0, 0);
        }
        int col = nt * 16 + m;
        float bias = bo[col];
#pragma unroll
        for (int i = 0; i < 4; ++i) {
            int row = r0 + quad * 4 + i;
            out[(size_t)row * DIM + col] = c[i] + bias;
        }
    }
}

extern "C" void kernel_launch(void* const* d_in, const int* in_sizes, int n_in,
                              void* d_out, int out_size, void* d_ws, size_t ws_size,
                              hipStream_t stream) {
    const float* x  = (const float*)d_in[0];
    const int*   ei = (const int*)d_in[1];      // [2, NE]: row0 = tgt, row1 = src
    const float* Wq = (const float*)d_in[2];
    const float* bq = (const float*)d_in[3];
    const float* Wk = (const float*)d_in[4];
    const float* bk = (const float*)d_in[5];
    const float* Wv = (const float*)d_in[6];
    const float* bv = (const float*)d_in[7];
    const float* Wo = (const float*)d_in[8];
    const float* bo = (const float*)d_in[9];

    const int* tgt = ei;
    const int* src = ei + NE;

    char* ws = (char*)d_ws;
    const size_t SZ_QV = (size_t)NN * QVROW * 2;    // 25.6 MB interleaved q+v
    const size_t SZ_BF = (size_t)NN * DIM * 2;      // 12.8 MB

    unsigned short* qvb  = (unsigned short*)(ws);
    unsigned short* kb   = (unsigned short*)(ws + SZ_QV);
    unsigned short* aggb = (unsigned short*)(ws + SZ_QV + SZ_BF);
    unsigned short* Wb   = (unsigned short*)(ws + SZ_QV + 2 * SZ_BF);  // 4 mats, 128 KB

    char* wi = ws + SZ_QV + 2 * SZ_BF + (size_t)4 * DIM * DIM * 2;
    int* cnt      = (int*)(wi);
    int* off      = (int*)(wi + (size_t)NN * 4);
    int* cursor   = (int*)(wi + (size_t)(2 * NN + 1) * 4);
    int* edge_src = (int*)(wi + (size_t)(3 * NN + 1) * 4);
    int* bsum     = (int*)(wi + (size_t)(3 * NN + 1) * 4 + (size_t)NE * 4);

    const int conv_blocks = (NW4 + NC4 + 255) / 256;
    const int edge_blocks = (NE + 255) / 256;  // 3125

    convert_kernel<<<conv_blocks, 256, 0, stream>>>(Wq, Wk, Wv, Wo, Wb, cnt);
    qkv_mfma_kernel<<<3 * TPB, 256, 0, stream>>>(x, Wb, bq, bk, bv, qvb, kb);
    hist_kernel<<<edge_blocks, 256, 0, stream>>>(tgt, cnt);
    scan1_kernel<<<SCAN_B, 256, 0, stream>>>(cnt, off, bsum);
    scan2_kernel<<<1, 256, 0, stream>>>(bsum, off);
    scan3_kernel<<<SCAN_B, 256, 0, stream>>>(off, bsum, cursor);
    fill_kernel<<<edge_blocks, 256, 0, stream>>>(tgt, src, cursor, edge_src);
    attn_kernel<<<(NN + 1) / 2, 256, 0, stream>>>(off, edge_src, qvb, kb, aggb);
    outproj_mfma_kernel<<<TPB, 256, 0, stream>>>(
        aggb, Wb + (size_t)3 * DIM * DIM, bo, (float*)d_out);
}

// Round 8
// 252.252 us; speedup vs baseline: 3.1252x; 1.1450x over previous
//
#include <hip/hip_runtime.h>
#include <math.h>

#define NN 50000
#define NE 800000
#define DIM 128
#define NH 8
#define HD 16
#define NTILE 3125            // NN/16 exactly
#define TPB 782               // ceil(NTILE/4) tile-groups per matrix
#define LROW 136              // LDS row stride in shorts (128 + 8 pad)
#define QVROW 256             // interleaved qv row: 256 shorts = 512 B
#define SCAN_B 196            // ceil(NN/256)

typedef short v8s __attribute__((ext_vector_type(8)));
typedef float v4f __attribute__((ext_vector_type(4)));

__device__ __forceinline__ unsigned short f2b(float f) {
    unsigned u = __float_as_uint(f);
    u = (u + 0x7fffu + ((u >> 16) & 1u)) >> 16;   // round-to-nearest-even
    return (unsigned short)u;
}
__device__ __forceinline__ float blo(unsigned w) { return __uint_as_float(w << 16); }
__device__ __forceinline__ float bhi(unsigned w) { return __uint_as_float(w & 0xffff0000u); }

// ---- K0: convert W{q,k,v,o} -> bf16 packed; zero cnt ----
#define NW4 (4 * DIM * DIM / 4)     // 16384 float4 of W
#define NC4 ((NN + 3) / 4)          // 12500 int4 of cnt
__global__ __launch_bounds__(256) void convert_kernel(
    const float* __restrict__ Wq, const float* __restrict__ Wk,
    const float* __restrict__ Wv, const float* __restrict__ Wo,
    unsigned short* __restrict__ Wb, int* __restrict__ cnt)
{
    int i = blockIdx.x * 256 + threadIdx.x;
    if (i < NW4) {
        int mat = i >> 12;            // 4096 float4 per matrix
        int off = i & 4095;
        const float* Wsrc = (mat == 0) ? Wq : (mat == 1) ? Wk : (mat == 2) ? Wv : Wo;
        float4 f = ((const float4*)Wsrc)[off];
        uint2 o;
        o.x = (unsigned)f2b(f.x) | ((unsigned)f2b(f.y) << 16);
        o.y = (unsigned)f2b(f.z) | ((unsigned)f2b(f.w) << 16);
        ((uint2*)(Wb + (size_t)mat * DIM * DIM))[off] = o;
    } else if (i < NW4 + NC4) {
        ((int4*)cnt)[i - NW4] = make_int4(0, 0, 0, 0);
    }
}

// ---- K1: QKV via MFMA (+ folded edge histogram). W staged in LDS. ----
__global__ __launch_bounds__(256) void qkv_mfma_kernel(
    const float* __restrict__ x, const unsigned short* __restrict__ Wb,
    const float* __restrict__ bq, const float* __restrict__ bk, const float* __restrict__ bv,
    unsigned short* __restrict__ qvb, unsigned short* __restrict__ kb,
    const int* __restrict__ tgt, int* __restrict__ cnt)
{
    __shared__ unsigned short Wl[DIM * LROW];   // 34816 B
    const int mat = blockIdx.x / TPB;           // 0=q, 1=k, 2=v
    const int tg  = blockIdx.x % TPB;
    const int tid = threadIdx.x;
    const int lane = tid & 63;
    const int warp = tid >> 6;
    const int m = lane & 15;
    const int quad = lane >> 4;

    // folded histogram: grid-stride over edges (fire-and-forget atomics)
    const int gsize = 3 * TPB * 256;
    for (int e = blockIdx.x * 256 + tid; e < NE; e += gsize)
        atomicAdd(cnt + tgt[e], 1);

    const unsigned short* Wg = Wb + (size_t)mat * DIM * DIM;
#pragma unroll
    for (int it = 0; it < 8; ++it) {
        int chunk = it * 256 + tid;           // 0..2047
        int row = chunk >> 4, c8 = chunk & 15;
        *(uint4*)(Wl + row * LROW + c8 * 8) = ((const uint4*)Wg)[chunk];
    }
    __syncthreads();

    const int rt = tg * 4 + warp;
    if (rt >= NTILE) return;
    const int r0 = rt * 16;

    const float* bias_p = (mat == 0) ? bq : (mat == 1) ? bk : bv;

    v8s a[4];
#pragma unroll
    for (int kt = 0; kt < 4; ++kt) {
        const float4* xr = (const float4*)(x + (size_t)(r0 + m) * DIM + kt * 32 + quad * 8);
        float4 f0 = xr[0], f1 = xr[1];
        v8s t;
        t[0] = (short)f2b(f0.x); t[1] = (short)f2b(f0.y);
        t[2] = (short)f2b(f0.z); t[3] = (short)f2b(f0.w);
        t[4] = (short)f2b(f1.x); t[5] = (short)f2b(f1.y);
        t[6] = (short)f2b(f1.z); t[7] = (short)f2b(f1.w);
        a[kt] = t;
    }

#pragma unroll
    for (int nt = 0; nt < 8; ++nt) {
        v4f c = {0.f, 0.f, 0.f, 0.f};
#pragma unroll
        for (int kt = 0; kt < 4; ++kt) {
            v8s b = *(const v8s*)(Wl + (nt * 16 + m) * LROW + kt * 32 + quad * 8);
            c = __builtin_amdgcn_mfma_f32_16x16x32_bf16(a[kt], b, c, 0, 0, 0);
        }
        int col = nt * 16 + m;           // C/D: col = lane&15
        float bias = bias_p[col];
#pragma unroll
        for (int i = 0; i < 4; ++i) {
            int row = r0 + quad * 4 + i; // C/D: row = quad*4 + reg
            unsigned short val = f2b(c[i] + bias);
            if (mat == 1) {
                kb[(size_t)row * DIM + col] = val;
            } else {
                int pos = (col >> 1) * 4 + (col & 1) + ((mat == 2) ? 2 : 0);
                qvb[(size_t)row * QVROW + pos] = val;
            }
        }
    }
}

// ---- K2: per-block (256-elem) local exclusive scan + block sums ----
__global__ __launch_bounds__(256) void scan1_kernel(
    const int* __restrict__ cnt, int* __restrict__ off, int* __restrict__ bsum)
{
    __shared__ int ws4[4];
    const int tid = threadIdx.x, lane = tid & 63, wid = tid >> 6;
    int i = blockIdx.x * 256 + tid;
    int v0 = (i < NN) ? cnt[i] : 0;
    int incl = v0;
#pragma unroll
    for (int d = 1; d < 64; d <<= 1) {
        int t = __shfl_up(incl, d);
        if (lane >= d) incl += t;
    }
    if (lane == 63) ws4[wid] = incl;
    __syncthreads();
    int wexcl = 0;
#pragma unroll
    for (int t = 0; t < 3; ++t) if (t < wid) wexcl += ws4[t];
    if (i < NN) off[i] = wexcl + incl - v0;
    if (tid == 255) bsum[blockIdx.x] = wexcl + incl;
}

// ---- K3: each block scans all 196 block sums (redundantly), adds its own
// base to off, inits cursor; last block writes off[NN] = total. ----
__global__ __launch_bounds__(256) void scan23_kernel(
    const int* __restrict__ bsum, int* __restrict__ off, int* __restrict__ cursor)
{
    __shared__ int ws4[4];
    __shared__ int base_s, total_s;
    const int tid = threadIdx.x, lane = tid & 63, wid = tid >> 6;
    int v0 = (tid < SCAN_B) ? bsum[tid] : 0;
    int incl = v0;
#pragma unroll
    for (int d = 1; d < 64; d <<= 1) {
        int t = __shfl_up(incl, d);
        if (lane >= d) incl += t;
    }
    if (lane == 63) ws4[wid] = incl;
    __syncthreads();
    int wexcl = 0;
#pragma unroll
    for (int t = 0; t < 3; ++t) if (t < wid) wexcl += ws4[t];
    int excl = wexcl + incl - v0;
    if (tid == blockIdx.x) base_s = excl;
    if (tid == SCAN_B - 1) total_s = excl + v0;
    __syncthreads();
    int i = blockIdx.x * 256 + tid;
    if (i < NN) {
        int t = off[i] + base_s;
        off[i] = t;
        cursor[i] = t;
    }
    if (blockIdx.x == SCAN_B - 1 && tid == 0) off[NN] = total_s;
}

// ---- K4: fill CSR (src only; tgt implicit in bucket) ----
__global__ __launch_bounds__(256) void fill_kernel(
    const int* __restrict__ tgt, const int* __restrict__ src,
    int* __restrict__ cursor, int* __restrict__ edge_src)
{
    int e = blockIdx.x * 256 + threadIdx.x;
    if (e >= NE) return;
    int t = tgt[e];
    int pos = atomicAdd(cursor + t, 1);
    edge_src[pos] = src[e];
}

// ---- K5: fused attention, 2 waves per node, batch-8 MLP + tree reduce.
// lane owns dims {2*lane, 2*lane+1}; head h = lane>>3 spans lanes 8h..8h+7.
// Per batch of 8 edges: 8 independent dwordx2 gathers; 3-stage select+xor
// tree leaves lane j (of the 8-lane group) holding edge j's full dot; ONE
// exp per lane per batch; p broadcast back via bpermute for the V accumulate.
// No max-subtraction: |score| = O(1) in fp32; normalization matches reference.
__global__ __launch_bounds__(256) void attn_kernel(
    const int* __restrict__ off, const int* __restrict__ edge_src,
    const unsigned short* __restrict__ qvb, const unsigned short* __restrict__ kb,
    unsigned short* __restrict__ aggb)
{
    __shared__ float red[2][64][3];
    const int tid = threadIdx.x;
    const int nib = tid >> 7;            // node-in-block (0..1)
    const int w   = (tid >> 6) & 1;      // wave half: even/odd edges
    const int lane = tid & 63;
    const int node = blockIdx.x * 2 + nib;

    const int base = off[node];
    const int deg  = off[node + 1] - base;

    unsigned kw = *(const unsigned*)(kb + (size_t)node * DIM + 2 * lane);
    const float klo = blo(kw), khi = bhi(kw);

    const int j = lane & 7;
    const int gb = lane & 56;            // 8-lane group base

    float ax = 0.f, ay = 0.f, ss = 0.f;
    const int nw = (deg + 1 - w) >> 1;   // edges for this wave: 2*i+w
    for (int c0 = 0; c0 < nw; c0 += 64) {
        int idx = c0 + lane;
        int srcv = edge_src[base + min(2 * idx + w, deg - 1)];
        int nchunk = min(nw - c0, 64);
        for (int b = 0; b < nchunk; b += 8) {
            int nb = min(nchunk - b, 8);
            uint2 qv[8];
#pragma unroll
            for (int i = 0; i < 8; ++i) {
                int si = __shfl(srcv, b + min(i, nb - 1));
                qv[i] = *(const uint2*)(qvb + (size_t)si * QVROW + 4 * lane);
            }
            float part[8];
#pragma unroll
            for (int i = 0; i < 8; ++i)
                part[i] = blo(qv[i].x) * klo + bhi(qv[i].x) * khi;
            // stage 1 (xor 1): pairs (0,1)(2,3)(4,5)(6,7)
            float r1[4];
#pragma unroll
            for (int t = 0; t < 4; ++t) {
                float keep = (j & 1) ? part[2 * t + 1] : part[2 * t];
                float send = (j & 1) ? part[2 * t]     : part[2 * t + 1];
                r1[t] = keep + __shfl_xor(send, 1);
            }
            // stage 2 (xor 2)
            float r2[2];
#pragma unroll
            for (int u = 0; u < 2; ++u) {
                float keep = (j & 2) ? r1[2 * u + 1] : r1[2 * u];
                float send = (j & 2) ? r1[2 * u]     : r1[2 * u + 1];
                r2[u] = keep + __shfl_xor(send, 2);
            }
            // stage 3 (xor 4): lane j now holds edge (b+j)'s full dot
            float keep = (j & 4) ? r2[1] : r2[0];
            float send = (j & 4) ? r2[0] : r2[1];
            float tot = keep + __shfl_xor(send, 4);
            float p = __expf(tot * 0.25f);   // 1/sqrt(HD)
            // broadcast p back and accumulate v
#pragma unroll
            for (int i = 0; i < 8; ++i) {
                if (i < nb) {
                    float pi = __shfl(p, gb + i);
                    unsigned vv = qv[i].y;
                    ax += pi * blo(vv);
                    ay += pi * bhi(vv);
                    ss += pi;
                }
            }
        }
    }
    if (w == 1) {
        red[nib][lane][0] = ax; red[nib][lane][1] = ay; red[nib][lane][2] = ss;
    }
    __syncthreads();
    if (w == 0) {
        ax += red[nib][lane][0]; ay += red[nib][lane][1]; ss += red[nib][lane][2];
        unsigned* ap = (unsigned*)(aggb + (size_t)node * DIM + 2 * lane);
        if (deg == 0) {
            *ap = 0u;
        } else {
            float inv = 1.f / ss;
            *ap = (unsigned)f2b(ax * inv) | ((unsigned)f2b(ay * inv) << 16);
        }
    }
}

// ---- K6: out = agg @ Wo.T + bo via MFMA, Wo staged in LDS, fp32 out ----
__global__ __launch_bounds__(256) void outproj_mfma_kernel(
    const unsigned short* __restrict__ aggb, const unsigned short* __restrict__ Wob,
    const float* __restrict__ bo, float* __restrict__ out)
{
    __shared__ unsigned short Wl[DIM * LROW];
    const int tid = threadIdx.x;
    const int lane = tid & 63;
    const int warp = tid >> 6;
    const int m = lane & 15;
    const int quad = lane >> 4;

#pragma unroll
    for (int it = 0; it < 8; ++it) {
        int chunk = it * 256 + tid;
        int row = chunk >> 4, c8 = chunk & 15;
        *(uint4*)(Wl + row * LROW + c8 * 8) = ((const uint4*)Wob)[chunk];
    }
    __syncthreads();

    const int rt = blockIdx.x * 4 + warp;
    if (rt >= NTILE) return;
    const int r0 = rt * 16;

    v8s a[4];
#pragma unroll
    for (int kt = 0; kt < 4; ++kt)
        a[kt] = *(const v8s*)(aggb + (size_t)(r0 + m) * DIM + kt * 32 + quad * 8);

#pragma unroll
    for (int nt = 0; nt < 8; ++nt) {
        v4f c = {0.f, 0.f, 0.f, 0.f};
#pragma unroll
        for (int kt = 0; kt < 4; ++kt) {
            v8s b = *(const v8s*)(Wl + (nt * 16 + m) * LROW + kt * 32 + quad * 8);
            c = __builtin_amdgcn_mfma_f32_16x16x32_bf16(a[kt], b, c, 0, 0, 0);
        }
        int col = nt * 16 + m;
        float bias = bo[col];
#pragma unroll
        for (int i = 0; i < 4; ++i) {
            int row = r0 + quad * 4 + i;
            out[(size_t)row * DIM + col] = c[i] + bias;
        }
    }
}

extern "C" void kernel_launch(void* const* d_in, const int* in_sizes, int n_in,
                              void* d_out, int out_size, void* d_ws, size_t ws_size,
                              hipStream_t stream) {
    const float* x  = (const float*)d_in[0];
    const int*   ei = (const int*)d_in[1];      // [2, NE]: row0 = tgt, row1 = src
    const float* Wq = (const float*)d_in[2];
    const float* bq = (const float*)d_in[3];
    const float* Wk = (const float*)d_in[4];
    const float* bk = (const float*)d_in[5];
    const float* Wv = (const float*)d_in[6];
    const float* bv = (const float*)d_in[7];
    const float* Wo = (const float*)d_in[8];
    const float* bo = (const float*)d_in[9];

    const int* tgt = ei;
    const int* src = ei + NE;

    char* ws = (char*)d_ws;
    const size_t SZ_QV = (size_t)NN * QVROW * 2;    // 25.6 MB interleaved q+v
    const size_t SZ_BF = (size_t)NN * DIM * 2;      // 12.8 MB

    unsigned short* qvb  = (unsigned short*)(ws);
    unsigned short* kb   = (unsigned short*)(ws + SZ_QV);
    unsigned short* aggb = (unsigned short*)(ws + SZ_QV + SZ_BF);
    unsigned short* Wb   = (unsigned short*)(ws + SZ_QV + 2 * SZ_BF);  // 4 mats, 128 KB

    char* wi = ws + SZ_QV + 2 * SZ_BF + (size_t)4 * DIM * DIM * 2;
    int* cnt      = (int*)(wi);
    int* off      = (int*)(wi + (size_t)NN * 4);
    int* cursor   = (int*)(wi + (size_t)(2 * NN + 1) * 4);
    int* edge_src = (int*)(wi + (size_t)(3 * NN + 1) * 4);
    int* bsum     = (int*)(wi + (size_t)(3 * NN + 1) * 4 + (size_t)NE * 4);

    const int conv_blocks = (NW4 + NC4 + 255) / 256;
    const int edge_blocks = (NE + 255) / 256;  // 3125

    convert_kernel<<<conv_blocks, 256, 0, stream>>>(Wq, Wk, Wv, Wo, Wb, cnt);
    qkv_mfma_kernel<<<3 * TPB, 256, 0, stream>>>(x, Wb, bq, bk, bv, qvb, kb, tgt, cnt);
    scan1_kernel<<<SCAN_B, 256, 0, stream>>>(cnt, off, bsum);
    scan23_kernel<<<SCAN_B, 256, 0, stream>>>(bsum, off, cursor);
    fill_kernel<<<edge_blocks, 256, 0, stream>>>(tgt, src, cursor, edge_src);
    attn_kernel<<<(NN + 1) / 2, 256, 0, stream>>>(off, edge_src, qvb, kb, aggb);
    outproj_mfma_kernel<<<TPB, 256, 0, stream>>>(
        aggb, Wb + (size_t)3 * DIM * DIM, bo, (float*)d_out);
}